// Round 7
// baseline (230.493 us; speedup 1.0000x reference)
//
#include <hip/hip_runtime.h>

#define DIM 1024
#define HEADS 16
#define BB 2
#define NN 2048
#define HD 64
#define M_ROWS (BB*NN)  // 4096

typedef __bf16 bf16x8 __attribute__((ext_vector_type(8)));
typedef float f32x4 __attribute__((ext_vector_type(4)));
typedef short s16x4 __attribute__((ext_vector_type(4)));

__device__ inline unsigned short f2bf(float f) {
    unsigned int u = __builtin_bit_cast(unsigned int, f);
    u += 0x7fffu + ((u >> 16) & 1u);
    return (unsigned short)(u >> 16);
}
__device__ inline float bf2f(unsigned short u) {
    return __builtin_bit_cast(float, (unsigned int)u << 16);
}
__device__ inline bf16x8 as_bf16x8(uint4 v) {
    return __builtin_bit_cast(bf16x8, v);
}
// async global->LDS, 16B per lane: LDS dest = base + lane*16 (wave-uniform
// base); global source address is per-lane (gather allowed).
__device__ __forceinline__ void gl_lds16(const unsigned short* g, unsigned short* l) {
    __builtin_amdgcn_global_load_lds(
        (const __attribute__((address_space(1))) unsigned int*)g,
        (__attribute__((address_space(3))) unsigned int*)l, 16, 0, 0);
}

// 16x16x16 bf16 MFMA (K=16): A/B = 4 bf16 (2 VGPRs), C/D = 4 f32.
__device__ __forceinline__ f32x4 mfma16x16x16bf16(s16x4 a, s16x4 b, f32x4 c) {
#if __has_builtin(__builtin_amdgcn_mfma_f32_16x16x16bf16_1k)
    return __builtin_amdgcn_mfma_f32_16x16x16bf16_1k(a, b, c, 0, 0, 0);
#else
    asm volatile("v_mfma_f32_16x16x16_bf16 %0, %1, %2, %0"
                 : "+v"(c) : "v"(a), "v"(b));
    return c;
#endif
}

// ---------------------------------------------------------------------------
// Weight prep: Wt[m][n][k] = W_m[k][n], f32 -> bf16.  grid (32,32,4), 256 thr.
// ---------------------------------------------------------------------------
__global__ __launch_bounds__(256) void prep_w(
    const float* __restrict__ Wq, const float* __restrict__ Wk,
    const float* __restrict__ Wv, const float* __restrict__ Wo,
    unsigned short* __restrict__ Wt_all)
{
    __shared__ float tile[32][33];
    const int m = blockIdx.z;
    const float* W = (m == 0) ? Wq : (m == 1) ? Wk : (m == 2) ? Wv : Wo;
    const int bk = blockIdx.x, bn = blockIdx.y;
    const int tx = threadIdx.x & 31, ty = threadIdx.x >> 5;  // 32 x 8

    #pragma unroll
    for (int i = 0; i < 32; i += 8)
        tile[ty + i][tx] = W[(size_t)(bk*32 + ty + i)*DIM + bn*32 + tx];
    __syncthreads();
    unsigned short* dst = Wt_all + (size_t)m * DIM * DIM;
    #pragma unroll
    for (int i = 0; i < 32; i += 8)
        dst[(size_t)(bn*32 + ty + i)*DIM + bk*32 + tx] = f2bf(tile[tx][ty + i]);
}

// ---------------------------------------------------------------------------
// Activation prep: Af=bf16(y2f), Ab=bf16(y2b), As=bf16(y2f+y2b). 8 el/thread.
// ---------------------------------------------------------------------------
__global__ __launch_bounds__(256) void prep_act(
    const float* __restrict__ y2f, const float* __restrict__ y2b,
    unsigned short* __restrict__ Af, unsigned short* __restrict__ Ab,
    unsigned short* __restrict__ As)
{
    const size_t idx = ((size_t)blockIdx.x*256 + threadIdx.x) * 8;
    #pragma unroll
    for (int half = 0; half < 2; half++) {
        float4 f = *(const float4*)(y2f + idx + half*4);
        float4 b = *(const float4*)(y2b + idx + half*4);
        ushort4 of, ob, os;
        of.x = f2bf(f.x); of.y = f2bf(f.y); of.z = f2bf(f.z); of.w = f2bf(f.w);
        ob.x = f2bf(b.x); ob.y = f2bf(b.y); ob.z = f2bf(b.z); ob.w = f2bf(b.w);
        os.x = f2bf(f.x + b.x); os.y = f2bf(f.y + b.y);
        os.z = f2bf(f.z + b.z); os.w = f2bf(f.w + b.w);
        *(ushort4*)(Af + idx + half*4) = of;
        *(ushort4*)(Ab + idx + half*4) = ob;
        *(ushort4*)(As + idx + half*4) = os;
    }
}

// ---------------------------------------------------------------------------
// Uniform QKV GEMM: grid (32, 24). bn>>3 selects mode (0=Q,1=K,2=V);
// every block: 128x128 tile, 32 K-iters over DIM=1024. m97 staging.
// Q -> Qh (head layout, pre-scaled 0.125*log2e); K -> Kh; V -> Vt [b,h,d,n].
// ---------------------------------------------------------------------------
__global__ __launch_bounds__(256) void gemm_qkv(
    const unsigned short* __restrict__ Af, const unsigned short* __restrict__ Ab,
    const unsigned short* __restrict__ As,
    const unsigned short* __restrict__ Wt_all,
    const float* __restrict__ bq, const float* __restrict__ bk,
    const float* __restrict__ bv,
    unsigned short* __restrict__ Qh, unsigned short* __restrict__ Kh,
    unsigned short* __restrict__ Vt)
{
    const int bm = blockIdx.x;
    const int mode = blockIdx.y >> 3;       // 0=Q, 1=K, 2=V
    const int bn = blockIdx.y & 7;
    __shared__ __align__(16) unsigned short sA[128*32];
    __shared__ __align__(16) unsigned short sB[128*32];
    const int t = threadIdx.x;
    const int w = t >> 6, lane = t & 63, ln = lane & 15, quad = lane >> 4;
    const int wm = w >> 1, wn = w & 1;
    const unsigned short* Wt = Wt_all + (size_t)mode * (DIM*DIM);
    const unsigned short* A0 = (mode == 0) ? Af : (mode == 1) ? Ab : As;

    const int srow = lane >> 2;
    const int scol = (lane & 3) * 8;

    f32x4 acc[4][4];
    #pragma unroll
    for (int mi = 0; mi < 4; mi++)
        #pragma unroll
        for (int ni = 0; ni < 4; ni++)
            acc[mi][ni] = (f32x4){0.f, 0.f, 0.f, 0.f};

    for (int kt = 0; kt < 32; kt++) {
        __syncthreads();
        #pragma unroll
        for (int j = 0; j < 2; j++) {
            int row = w*32 + j*16;
            gl_lds16(A0 + (size_t)(bm*128 + row + srow)*DIM + kt*32 + scol,
                     &sA[row*32]);
            gl_lds16(Wt + (size_t)(bn*128 + row + srow)*DIM + kt*32 + scol,
                     &sB[row*32]);
        }
        __syncthreads();

        bf16x8 af[4], bfr[4];
        #pragma unroll
        for (int mi = 0; mi < 4; mi++)
            af[mi] = as_bf16x8(*(const uint4*)(&sA[(wm*64 + mi*16 + ln)*32 + quad*8]));
        #pragma unroll
        for (int ni = 0; ni < 4; ni++)
            bfr[ni] = as_bf16x8(*(const uint4*)(&sB[(wn*64 + ni*16 + ln)*32 + quad*8]));
        #pragma unroll
        for (int mi = 0; mi < 4; mi++)
            #pragma unroll
            for (int ni = 0; ni < 4; ni++)
                acc[mi][ni] = __builtin_amdgcn_mfma_f32_16x16x32_bf16(af[mi], bfr[ni], acc[mi][ni], 0, 0, 0);
    }

    const float* bias = (mode == 0) ? bq : (mode == 1) ? bk : bv;
    unsigned short* dst = (mode == 0) ? Qh : (mode == 1) ? Kh : Vt;
    const float sc = (mode == 0) ? 0.125f * 1.4426950408889634f : 1.0f;
    #pragma unroll
    for (int mi = 0; mi < 4; mi++) {
        #pragma unroll
        for (int r = 0; r < 4; r++) {
            int grow = bm*128 + wm*64 + mi*16 + quad*4 + r;
            int b_ = grow >> 11, n = grow & (NN - 1);
            #pragma unroll
            for (int ni = 0; ni < 4; ni++) {
                int gcol = bn*128 + wn*64 + ni*16 + ln;
                int hh = gcol >> 6, dd = gcol & 63;
                float val = (acc[mi][ni][r] + bias[gcol]) * sc;
                if (mode == 2)  // write V transposed: Vt[b,h,d,n]
                    dst[(((size_t)(b_*HEADS + hh))*HD + dd)*NN + n] = f2bf(val);
                else
                    dst[(((size_t)(b_*HEADS + hh))*NN + n)*HD + dd] = f2bf(val);
            }
        }
    }
}

// ---------------------------------------------------------------------------
// Out projection: out[4096,1024] = attp @ Wo^T + bo (f32).
// 64x128 tile, grid (64, 8) = 512 blocks (2/CU).
// ---------------------------------------------------------------------------
__global__ __launch_bounds__(256) void gemm_out(
    const unsigned short* __restrict__ attp,
    const unsigned short* __restrict__ Wt_all,
    const float* __restrict__ bo, float* __restrict__ out)
{
    const int bm = blockIdx.x, bn = blockIdx.y;
    __shared__ __align__(16) unsigned short sA[64*32];
    __shared__ __align__(16) unsigned short sB[128*32];
    const int t = threadIdx.x;
    const int w = t >> 6, lane = t & 63, ln = lane & 15, quad = lane >> 4;
    const int wm = w >> 1, wn = w & 1;
    const unsigned short* Wt = Wt_all + (size_t)3 * (DIM*DIM);

    const int srow = lane >> 2;
    const int scol = (lane & 3) * 8;

    f32x4 acc[2][4];
    #pragma unroll
    for (int mi = 0; mi < 2; mi++)
        #pragma unroll
        for (int ni = 0; ni < 4; ni++)
            acc[mi][ni] = (f32x4){0.f, 0.f, 0.f, 0.f};

    for (int kt = 0; kt < 32; kt++) {
        __syncthreads();
        gl_lds16(attp + (size_t)(bm*64 + w*16 + srow)*DIM + kt*32 + scol,
                 &sA[(w*16)*32]);
        #pragma unroll
        for (int j = 0; j < 2; j++) {
            int row = w*32 + j*16;
            gl_lds16(Wt + (size_t)(bn*128 + row + srow)*DIM + kt*32 + scol,
                     &sB[row*32]);
        }
        __syncthreads();

        bf16x8 af[2], bfr[4];
        #pragma unroll
        for (int mi = 0; mi < 2; mi++)
            af[mi] = as_bf16x8(*(const uint4*)(&sA[(wm*32 + mi*16 + ln)*32 + quad*8]));
        #pragma unroll
        for (int ni = 0; ni < 4; ni++)
            bfr[ni] = as_bf16x8(*(const uint4*)(&sB[(wn*64 + ni*16 + ln)*32 + quad*8]));
        #pragma unroll
        for (int mi = 0; mi < 2; mi++)
            #pragma unroll
            for (int ni = 0; ni < 4; ni++)
                acc[mi][ni] = __builtin_amdgcn_mfma_f32_16x16x32_bf16(af[mi], bfr[ni], acc[mi][ni], 0, 0, 0);
    }

    #pragma unroll
    for (int mi = 0; mi < 2; mi++) {
        #pragma unroll
        for (int r = 0; r < 4; r++) {
            int grow = bm*64 + wm*32 + mi*16 + quad*4 + r;
            #pragma unroll
            for (int ni = 0; ni < 4; ni++) {
                int gcol = bn*128 + wn*64 + ni*16 + ln;
                out[(size_t)grow*DIM + gcol] = acc[mi][ni][r] + bo[gcol];
            }
        }
    }
}

// ---------------------------------------------------------------------------
// Flash attention v3: register-P, hoisted Q frags, KV=128 per barrier,
// ones-MFMA row-sums, v_perm packing, DMA-staged XOR-swizzled LDS.
//   S^T = mfma32(A=K, B=Q): lane holds q-col=ln, kv=quad*4+r (C-layout) ==
//   A-frag of 16x16x16 MFMA -> P feeds PV and L-accum from registers.
// Fixed-max exp2 softmax (Q pre-scaled by 0.125*log2e; bias 12*log2e).
// 64 q-rows/block, grid (32 bh, 32 qt) = 1024 blocks; LDS 40KB -> 4/CU.
// ---------------------------------------------------------------------------
__global__ __launch_bounds__(256) void attn_kernel(
    const unsigned short* __restrict__ Qh, const unsigned short* __restrict__ Kh,
    const unsigned short* __restrict__ Vt, const unsigned short* __restrict__ As,
    unsigned short* __restrict__ attp)
{
    const int bh = blockIdx.x;      // b*16 + h
    const int qt = blockIdx.y;      // 0..31 (64-row q tiles)
    const int b = bh >> 4, h = bh & 15;
    const int t = threadIdx.x;
    const int w = t >> 6, lane = t & 63, ln = lane & 15, quad = lane >> 4;
    const int sw = ln & 7;          // fragment rows are == ln (mod 8)
    const float EBIAS = 17.312340490667562f;   // 12 * log2(e)

    __shared__ __align__(16) unsigned short sQ[64*64];     // 8 KB
    __shared__ __align__(16) unsigned short sK[128*64];    // 16 KB [n][k]
    __shared__ __align__(16) unsigned short sVt[64*128];   // 16 KB [d][n]

    const unsigned short* Qb  = Qh + (size_t)bh * NN * HD + (size_t)qt * 64 * HD;
    const unsigned short* Kb  = Kh + (size_t)bh * NN * HD;
    const unsigned short* Vtb = Vt + (size_t)bh * HD * NN;   // [d][n]

    // ---- stage Q once; hoist the wave's Q fragments into registers ----
    {
        const int rl = lane >> 3, cb = lane & 7;
        #pragma unroll
        for (int j = 0; j < 2; j++) {
            int row = w*16 + j*8 + rl;
            gl_lds16(Qb + (size_t)row*HD + ((cb ^ (row & 7))*8),
                     &sQ[(w*16 + j*8)*64]);
        }
    }
    __syncthreads();
    bf16x8 aq[2];
    #pragma unroll
    for (int k = 0; k < 2; k++)
        aq[k] = as_bf16x8(*(const uint4*)(&sQ[(w*16 + ln)*64 + (((k*4 + quad) ^ sw)*8)]));

    const s16x4 ones = { (short)0x3F80, (short)0x3F80, (short)0x3F80, (short)0x3F80 };
    f32x4 accO[4], accL;
    accL = (f32x4){0.f, 0.f, 0.f, 0.f};
    #pragma unroll
    for (int di = 0; di < 4; di++) accO[di] = (f32x4){0.f, 0.f, 0.f, 0.f};

    for (int jt = 0; jt < 16; jt++) {
        __syncthreads();
        // stage K rows [w*32, w*32+32): 8 blocks/row, swizzle cb^(row&7)
        {
            const int rl = lane >> 3, p = lane & 7;
            #pragma unroll
            for (int j = 0; j < 4; j++) {
                int row = w*32 + j*8 + rl;
                gl_lds16(Kb + (size_t)(jt*128 + row)*HD + ((p ^ (row & 7))*8),
                         &sK[(w*32 + j*8)*64]);
            }
        }
        // stage V^T rows d [w*16, w*16+16): 16 blocks/row,
        // LDS pos p holds global block (p&8)|((p&7)^(d&7))
        {
            const int rl = lane >> 4, p = lane & 15;
            #pragma unroll
            for (int j = 0; j < 4; j++) {
                int d = w*16 + j*4 + rl;
                int cb = (p & 8) | ((p & 7) ^ (d & 7));
                gl_lds16(Vtb + (size_t)d*NN + jt*128 + cb*8,
                         &sVt[(w*16 + j*4)*128]);
            }
        }
        __syncthreads();

        #pragma unroll
        for (int g = 0; g < 2; g++) {
            // S^T for kv block group g (4 x 16 kv)
            f32x4 accS[4];
            #pragma unroll
            for (int ni = 0; ni < 4; ni++) accS[ni] = (f32x4){0.f, 0.f, 0.f, 0.f};
            #pragma unroll
            for (int ni = 0; ni < 4; ni++) {
                int nn = g*4 + ni;
                #pragma unroll
                for (int k = 0; k < 2; k++) {
                    bf16x8 bk = as_bf16x8(*(const uint4*)(
                        &sK[(nn*16 + ln)*64 + (((k*4 + quad) ^ sw)*8)]));
                    accS[ni] = __builtin_amdgcn_mfma_f32_16x16x32_bf16(bk, aq[k], accS[ni], 0, 0, 0);
                }
            }
            // p = exp2(s-EBIAS); pack via v_perm (trunc); L via ones-MFMA
            s16x4 pf[4];
            #pragma unroll
            for (int ni = 0; ni < 4; ni++) {
                unsigned int e0 = __builtin_bit_cast(unsigned int, __builtin_amdgcn_exp2f(accS[ni][0] - EBIAS));
                unsigned int e1 = __builtin_bit_cast(unsigned int, __builtin_amdgcn_exp2f(accS[ni][1] - EBIAS));
                unsigned int e2 = __builtin_bit_cast(unsigned int, __builtin_amdgcn_exp2f(accS[ni][2] - EBIAS));
                unsigned int e3 = __builtin_bit_cast(unsigned int, __builtin_amdgcn_exp2f(accS[ni][3] - EBIAS));
                unsigned int lo = __builtin_amdgcn_perm(e1, e0, 0x07060302u);
                unsigned int hi = __builtin_amdgcn_perm(e3, e2, 0x07060302u);
                pf[ni] = __builtin_bit_cast(s16x4, uint2{lo, hi});
                accL = mfma16x16x16bf16(pf[ni], ones, accL);
            }
            // O += P V
            #pragma unroll
            for (int ni = 0; ni < 4; ni++) {
                int nn = g*4 + ni;
                int cbase = 2*nn + (quad >> 1);                  // 0..15
                int p = (cbase & 8) | ((cbase & 7) ^ sw);
                int off = (quad & 1)*4;
                #pragma unroll
                for (int di = 0; di < 4; di++) {
                    s16x4 bv = __builtin_bit_cast(s16x4,
                        *(const uint2*)(&sVt[(di*16 + ln)*128 + p*8 + off]));
                    accO[di] = mfma16x16x16bf16(pf[ni], bv, accO[di]);
                }
            }
        }
    }

    // accL[r] = row-sum L for q-row w*16+quad*4+r (uniform over ln)
    #pragma unroll
    for (int r = 0; r < 4; r++) {
        float inv = 1.f / accL[r];
        int n = qt*64 + w*16 + quad*4 + r;
        #pragma unroll
        for (int di = 0; di < 4; di++) {
            int c = h*64 + di*16 + ln;
            size_t gi = ((size_t)b*NN + n)*DIM + c;
            float o = accO[di][r]*inv + bf2f(As[gi]);
            attp[gi] = f2bf(o);
        }
    }
}

// ---------------------------------------------------------------------------
extern "C" void kernel_launch(void* const* d_in, const int* in_sizes, int n_in,
                              void* d_out, int out_size, void* d_ws, size_t ws_size,
                              hipStream_t stream) {
    const float* y2f = (const float*)d_in[0];
    const float* y2b = (const float*)d_in[1];
    const float* Wq  = (const float*)d_in[2];
    const float* bq  = (const float*)d_in[3];
    const float* Wk  = (const float*)d_in[4];
    const float* bk  = (const float*)d_in[5];
    const float* Wv  = (const float*)d_in[6];
    const float* bv  = (const float*)d_in[7];
    const float* Wo  = (const float*)d_in[8];
    const float* bo  = (const float*)d_in[9];
    float* out = (float*)d_out;

    const size_t NACT = (size_t)M_ROWS * DIM;  // 4,194,304 (8 MB as ushort)
    unsigned short* ws   = (unsigned short*)d_ws;
    unsigned short* Af   = ws;
    unsigned short* Ab   = ws + NACT;
    unsigned short* As   = ws + 2*NACT;
    unsigned short* Qh   = ws + 3*NACT;
    unsigned short* Kh   = ws + 4*NACT;
    unsigned short* Vt   = ws + 5*NACT;   // V written pre-transposed [b,h,d,n]
    unsigned short* Wt   = ws + 6*NACT;   // 4 x 1024 x 1024 bf16
    unsigned short* attp = Ab;            // overlay (Ab dead after QKV gemm)

    prep_w<<<dim3(32, 32, 4), 256, 0, stream>>>(Wq, Wk, Wv, Wo, Wt);
    prep_act<<<dim3(2048), 256, 0, stream>>>(y2f, y2b, Af, Ab, As);
    gemm_qkv<<<dim3(32, 24), 256, 0, stream>>>(
        Af, Ab, As, Wt, bq, bk, bv, Qh, Kh, Vt);
    attn_kernel<<<dim3(32, 32), 256, 0, stream>>>(Qh, Kh, Vt, As, attp);
    gemm_out<<<dim3(64, 8), 256, 0, stream>>>(attp, Wt, bo, out);
}

// Round 8
// 223.217 us; speedup vs baseline: 1.0326x; 1.0326x over previous
//
#include <hip/hip_runtime.h>

#define DIM 1024
#define HEADS 16
#define BB 2
#define NN 2048
#define HD 64
#define M_ROWS (BB*NN)  // 4096

typedef __bf16 bf16x8 __attribute__((ext_vector_type(8)));
typedef float f32x4 __attribute__((ext_vector_type(4)));
typedef short s16x4 __attribute__((ext_vector_type(4)));

__device__ inline unsigned short f2bf(float f) {
    unsigned int u = __builtin_bit_cast(unsigned int, f);
    u += 0x7fffu + ((u >> 16) & 1u);
    return (unsigned short)(u >> 16);
}
__device__ inline float bf2f(unsigned short u) {
    return __builtin_bit_cast(float, (unsigned int)u << 16);
}
__device__ inline bf16x8 as_bf16x8(uint4 v) {
    return __builtin_bit_cast(bf16x8, v);
}
// async global->LDS, 16B per lane: LDS dest = base + lane*16 (wave-uniform
// base); global source address is per-lane (gather allowed).
__device__ __forceinline__ void gl_lds16(const unsigned short* g, unsigned short* l) {
    __builtin_amdgcn_global_load_lds(
        (const __attribute__((address_space(1))) unsigned int*)g,
        (__attribute__((address_space(3))) unsigned int*)l, 16, 0, 0);
}

// 16x16x16 bf16 MFMA (K=16): A/B = 4 bf16 (2 VGPRs), C/D = 4 f32.
__device__ __forceinline__ f32x4 mfma16x16x16bf16(s16x4 a, s16x4 b, f32x4 c) {
#if __has_builtin(__builtin_amdgcn_mfma_f32_16x16x16bf16_1k)
    return __builtin_amdgcn_mfma_f32_16x16x16bf16_1k(a, b, c, 0, 0, 0);
#else
    asm volatile("v_mfma_f32_16x16x16_bf16 %0, %1, %2, %0"
                 : "+v"(c) : "v"(a), "v"(b));
    return c;
#endif
}

// ---------------------------------------------------------------------------
// Weight prep: Wt[m][n][k] = W_m[k][n], f32 -> bf16.  grid (32,32,4), 256 thr.
// ---------------------------------------------------------------------------
__global__ __launch_bounds__(256) void prep_w(
    const float* __restrict__ Wq, const float* __restrict__ Wk,
    const float* __restrict__ Wv, const float* __restrict__ Wo,
    unsigned short* __restrict__ Wt_all)
{
    __shared__ float tile[32][33];
    const int m = blockIdx.z;
    const float* W = (m == 0) ? Wq : (m == 1) ? Wk : (m == 2) ? Wv : Wo;
    const int bk = blockIdx.x, bn = blockIdx.y;
    const int tx = threadIdx.x & 31, ty = threadIdx.x >> 5;  // 32 x 8

    #pragma unroll
    for (int i = 0; i < 32; i += 8)
        tile[ty + i][tx] = W[(size_t)(bk*32 + ty + i)*DIM + bn*32 + tx];
    __syncthreads();
    unsigned short* dst = Wt_all + (size_t)m * DIM * DIM;
    #pragma unroll
    for (int i = 0; i < 32; i += 8)
        dst[(size_t)(bn*32 + ty + i)*DIM + bk*32 + tx] = f2bf(tile[tx][ty + i]);
}

// ---------------------------------------------------------------------------
// Activation prep: Af=bf16(y2f), Ab=bf16(y2b), As=bf16(y2f+y2b). 8 el/thread.
// ---------------------------------------------------------------------------
__global__ __launch_bounds__(256) void prep_act(
    const float* __restrict__ y2f, const float* __restrict__ y2b,
    unsigned short* __restrict__ Af, unsigned short* __restrict__ Ab,
    unsigned short* __restrict__ As)
{
    const size_t idx = ((size_t)blockIdx.x*256 + threadIdx.x) * 8;
    #pragma unroll
    for (int half = 0; half < 2; half++) {
        float4 f = *(const float4*)(y2f + idx + half*4);
        float4 b = *(const float4*)(y2b + idx + half*4);
        ushort4 of, ob, os;
        of.x = f2bf(f.x); of.y = f2bf(f.y); of.z = f2bf(f.z); of.w = f2bf(f.w);
        ob.x = f2bf(b.x); ob.y = f2bf(b.y); ob.z = f2bf(b.z); ob.w = f2bf(b.w);
        os.x = f2bf(f.x + b.x); os.y = f2bf(f.y + b.y);
        os.z = f2bf(f.z + b.z); os.w = f2bf(f.w + b.w);
        *(ushort4*)(Af + idx + half*4) = of;
        *(ushort4*)(Ab + idx + half*4) = ob;
        *(ushort4*)(As + idx + half*4) = os;
    }
}

// ---------------------------------------------------------------------------
// Uniform QKV GEMM: grid (32, 24). bn>>3 selects mode (0=Q,1=K,2=V);
// every block: 128x128 tile, 32 K-iters over DIM=1024. m97 staging.
// Q -> Qh (head layout, pre-scaled 0.125*log2e); K -> Kh; V -> Vt [b,h,d,n].
// ---------------------------------------------------------------------------
__global__ __launch_bounds__(256) void gemm_qkv(
    const unsigned short* __restrict__ Af, const unsigned short* __restrict__ Ab,
    const unsigned short* __restrict__ As,
    const unsigned short* __restrict__ Wt_all,
    const float* __restrict__ bq, const float* __restrict__ bk,
    const float* __restrict__ bv,
    unsigned short* __restrict__ Qh, unsigned short* __restrict__ Kh,
    unsigned short* __restrict__ Vt)
{
    const int bm = blockIdx.x;
    const int mode = blockIdx.y >> 3;       // 0=Q, 1=K, 2=V
    const int bn = blockIdx.y & 7;
    __shared__ __align__(16) unsigned short sA[128*32];
    __shared__ __align__(16) unsigned short sB[128*32];
    const int t = threadIdx.x;
    const int w = t >> 6, lane = t & 63, ln = lane & 15, quad = lane >> 4;
    const int wm = w >> 1, wn = w & 1;
    const unsigned short* Wt = Wt_all + (size_t)mode * (DIM*DIM);
    const unsigned short* A0 = (mode == 0) ? Af : (mode == 1) ? Ab : As;

    const int srow = lane >> 2;
    const int scol = (lane & 3) * 8;

    f32x4 acc[4][4];
    #pragma unroll
    for (int mi = 0; mi < 4; mi++)
        #pragma unroll
        for (int ni = 0; ni < 4; ni++)
            acc[mi][ni] = (f32x4){0.f, 0.f, 0.f, 0.f};

    for (int kt = 0; kt < 32; kt++) {
        __syncthreads();
        #pragma unroll
        for (int j = 0; j < 2; j++) {
            int row = w*32 + j*16;
            gl_lds16(A0 + (size_t)(bm*128 + row + srow)*DIM + kt*32 + scol,
                     &sA[row*32]);
            gl_lds16(Wt + (size_t)(bn*128 + row + srow)*DIM + kt*32 + scol,
                     &sB[row*32]);
        }
        __syncthreads();

        bf16x8 af[4], bfr[4];
        #pragma unroll
        for (int mi = 0; mi < 4; mi++)
            af[mi] = as_bf16x8(*(const uint4*)(&sA[(wm*64 + mi*16 + ln)*32 + quad*8]));
        #pragma unroll
        for (int ni = 0; ni < 4; ni++)
            bfr[ni] = as_bf16x8(*(const uint4*)(&sB[(wn*64 + ni*16 + ln)*32 + quad*8]));
        #pragma unroll
        for (int mi = 0; mi < 4; mi++)
            #pragma unroll
            for (int ni = 0; ni < 4; ni++)
                acc[mi][ni] = __builtin_amdgcn_mfma_f32_16x16x32_bf16(af[mi], bfr[ni], acc[mi][ni], 0, 0, 0);
    }

    const float* bias = (mode == 0) ? bq : (mode == 1) ? bk : bv;
    unsigned short* dst = (mode == 0) ? Qh : (mode == 1) ? Kh : Vt;
    const float sc = (mode == 0) ? 0.125f * 1.4426950408889634f : 1.0f;
    #pragma unroll
    for (int mi = 0; mi < 4; mi++) {
        #pragma unroll
        for (int r = 0; r < 4; r++) {
            int grow = bm*128 + wm*64 + mi*16 + quad*4 + r;
            int b_ = grow >> 11, n = grow & (NN - 1);
            #pragma unroll
            for (int ni = 0; ni < 4; ni++) {
                int gcol = bn*128 + wn*64 + ni*16 + ln;
                int hh = gcol >> 6, dd = gcol & 63;
                float val = (acc[mi][ni][r] + bias[gcol]) * sc;
                if (mode == 2)  // write V transposed: Vt[b,h,d,n]
                    dst[(((size_t)(b_*HEADS + hh))*HD + dd)*NN + n] = f2bf(val);
                else
                    dst[(((size_t)(b_*HEADS + hh))*NN + n)*HD + dd] = f2bf(val);
            }
        }
    }
}

// ---------------------------------------------------------------------------
// Out projection: out[4096,1024] = attp @ Wo^T + bo (f32).
// 64x128 tile, grid (64, 8) = 512 blocks (2/CU).
// ---------------------------------------------------------------------------
__global__ __launch_bounds__(256) void gemm_out(
    const unsigned short* __restrict__ attp,
    const unsigned short* __restrict__ Wt_all,
    const float* __restrict__ bo, float* __restrict__ out)
{
    const int bm = blockIdx.x, bn = blockIdx.y;
    __shared__ __align__(16) unsigned short sA[64*32];
    __shared__ __align__(16) unsigned short sB[128*32];
    const int t = threadIdx.x;
    const int w = t >> 6, lane = t & 63, ln = lane & 15, quad = lane >> 4;
    const int wm = w >> 1, wn = w & 1;
    const unsigned short* Wt = Wt_all + (size_t)3 * (DIM*DIM);

    const int srow = lane >> 2;
    const int scol = (lane & 3) * 8;

    f32x4 acc[2][4];
    #pragma unroll
    for (int mi = 0; mi < 2; mi++)
        #pragma unroll
        for (int ni = 0; ni < 4; ni++)
            acc[mi][ni] = (f32x4){0.f, 0.f, 0.f, 0.f};

    for (int kt = 0; kt < 32; kt++) {
        __syncthreads();
        gl_lds16(attp + (size_t)(bm*64 + w*16 + srow)*DIM + kt*32 + scol,
                 &sA[(w*16)*32]);
        #pragma unroll
        for (int j = 0; j < 2; j++) {
            int row = w*32 + j*16;
            gl_lds16(Wt + (size_t)(bn*128 + row + srow)*DIM + kt*32 + scol,
                     &sB[row*32]);
        }
        __syncthreads();

        bf16x8 af[2], bfr[4];
        #pragma unroll
        for (int mi = 0; mi < 2; mi++)
            af[mi] = as_bf16x8(*(const uint4*)(&sA[(wm*32 + mi*16 + ln)*32 + quad*8]));
        #pragma unroll
        for (int ni = 0; ni < 4; ni++)
            bfr[ni] = as_bf16x8(*(const uint4*)(&sB[(wn*64 + ni*16 + ln)*32 + quad*8]));
        #pragma unroll
        for (int mi = 0; mi < 2; mi++)
            #pragma unroll
            for (int ni = 0; ni < 4; ni++)
                acc[mi][ni] = __builtin_amdgcn_mfma_f32_16x16x32_bf16(af[mi], bfr[ni], acc[mi][ni], 0, 0, 0);
    }

    #pragma unroll
    for (int mi = 0; mi < 2; mi++) {
        #pragma unroll
        for (int r = 0; r < 4; r++) {
            int grow = bm*64 + wm*32 + mi*16 + quad*4 + r;
            #pragma unroll
            for (int ni = 0; ni < 4; ni++) {
                int gcol = bn*128 + wn*64 + ni*16 + ln;
                out[(size_t)grow*DIM + gcol] = acc[mi][ni][r] + bo[gcol];
            }
        }
    }
}

// ---------------------------------------------------------------------------
// Flash attention v4 = R5 structure (KV=64, 24KB LDS, 6 blocks/CU) +
// R7 VALU cuts (hoisted Q frags, ones-MFMA row-sums, v_perm packing,
// As-based epilogue). Register-P path:
//   S^T = mfma32(A=K, B=Q): lane holds q-col=ln, kv=quad*4+r (C-layout) ==
//   A-frag of 16x16x16 MFMA -> P feeds PV and L-accum from registers.
// Fixed-max exp2 softmax (Q pre-scaled by 0.125*log2e; bias 12*log2e).
// 64 q-rows/block, grid (32 bh, 32 qt) = 1024 blocks.
// ---------------------------------------------------------------------------
__global__ __launch_bounds__(256) void attn_kernel(
    const unsigned short* __restrict__ Qh, const unsigned short* __restrict__ Kh,
    const unsigned short* __restrict__ Vt, const unsigned short* __restrict__ As,
    unsigned short* __restrict__ attp)
{
    const int bh = blockIdx.x;      // b*16 + h
    const int qt = blockIdx.y;      // 0..31 (64-row q tiles)
    const int b = bh >> 4, h = bh & 15;
    const int t = threadIdx.x;
    const int w = t >> 6, lane = t & 63, ln = lane & 15, quad = lane >> 4;
    const int sw = ln & 7;          // fragment rows are == ln (mod 8)
    const float EBIAS = 17.312340490667562f;   // 12 * log2(e)

    __shared__ __align__(16) unsigned short sQ[64*64];     // 8 KB
    __shared__ __align__(16) unsigned short sK[64*64];     // 8 KB [n][k]
    __shared__ __align__(16) unsigned short sVt[64*64];    // 8 KB [d][n]

    const unsigned short* Qb  = Qh + (size_t)bh * NN * HD + (size_t)qt * 64 * HD;
    const unsigned short* Kb  = Kh + (size_t)bh * NN * HD;
    const unsigned short* Vtb = Vt + (size_t)bh * HD * NN;   // [d][n]

    const int rl = lane >> 3, cb = lane & 7;

    // ---- stage Q once; hoist the wave's Q fragments into registers ----
    #pragma unroll
    for (int j = 0; j < 2; j++) {
        int row = w*16 + j*8 + rl;
        gl_lds16(Qb + (size_t)row*HD + ((cb ^ (row & 7))*8), &sQ[(w*16 + j*8)*64]);
    }
    __syncthreads();
    bf16x8 aq[2];
    #pragma unroll
    for (int k = 0; k < 2; k++)
        aq[k] = as_bf16x8(*(const uint4*)(&sQ[(w*16 + ln)*64 + (((k*4 + quad) ^ sw)*8)]));

    const s16x4 ones = { (short)0x3F80, (short)0x3F80, (short)0x3F80, (short)0x3F80 };
    f32x4 accO[4], accL;
    accL = (f32x4){0.f, 0.f, 0.f, 0.f};
    #pragma unroll
    for (int di = 0; di < 4; di++) accO[di] = (f32x4){0.f, 0.f, 0.f, 0.f};

    for (int jt = 0; jt < 32; jt++) {
        __syncthreads();
        #pragma unroll
        for (int j = 0; j < 2; j++) {
            int row = w*16 + j*8 + rl;
            gl_lds16(Kb + (size_t)(jt*64 + row)*HD + ((cb ^ (row & 7))*8),
                     &sK[(w*16 + j*8)*64]);
            gl_lds16(Vtb + (size_t)row*NN + jt*64 + ((cb ^ (row & 7))*8),
                     &sVt[(w*16 + j*8)*64]);
        }
        __syncthreads();

        // S^T: accS[ni] — lane: q-col = w*16+ln, kv = ni*16+quad*4+r
        f32x4 accS[4];
        #pragma unroll
        for (int ni = 0; ni < 4; ni++) accS[ni] = (f32x4){0.f, 0.f, 0.f, 0.f};
        #pragma unroll
        for (int ni = 0; ni < 4; ni++)
            #pragma unroll
            for (int k = 0; k < 2; k++) {
                bf16x8 bk = as_bf16x8(*(const uint4*)(
                    &sK[(ni*16 + ln)*64 + (((k*4 + quad) ^ sw)*8)]));
                accS[ni] = __builtin_amdgcn_mfma_f32_16x16x32_bf16(bk, aq[k], accS[ni], 0, 0, 0);
            }

        // p = exp2(s-EBIAS); pack via v_perm (trunc); L via ones-MFMA
        s16x4 pf[4];
        #pragma unroll
        for (int ni = 0; ni < 4; ni++) {
            unsigned int e0 = __builtin_bit_cast(unsigned int, __builtin_amdgcn_exp2f(accS[ni][0] - EBIAS));
            unsigned int e1 = __builtin_bit_cast(unsigned int, __builtin_amdgcn_exp2f(accS[ni][1] - EBIAS));
            unsigned int e2 = __builtin_bit_cast(unsigned int, __builtin_amdgcn_exp2f(accS[ni][2] - EBIAS));
            unsigned int e3 = __builtin_bit_cast(unsigned int, __builtin_amdgcn_exp2f(accS[ni][3] - EBIAS));
            unsigned int lo = __builtin_amdgcn_perm(e1, e0, 0x07060302u);
            unsigned int hi = __builtin_amdgcn_perm(e3, e2, 0x07060302u);
            pf[ni] = __builtin_bit_cast(s16x4, uint2{lo, hi});
            accL = mfma16x16x16bf16(pf[ni], ones, accL);
        }

        // O += P V: B-frag = V^T[d=di*16+ln][kv=ni*16+quad*4+j], 8-B read
        #pragma unroll
        for (int ni = 0; ni < 4; ni++) {
            int blkv = 2*ni + (quad >> 1);
            int off = (quad & 1) * 4;
            #pragma unroll
            for (int di = 0; di < 4; di++) {
                s16x4 bv = __builtin_bit_cast(s16x4,
                    *(const uint2*)(&sVt[(di*16 + ln)*64 + ((blkv ^ sw)*8) + off]));
                accO[di] = mfma16x16x16bf16(pf[ni], bv, accO[di]);
            }
        }
    }

    // accL[r] = row-sum L for q-row w*16+quad*4+r (uniform over ln)
    #pragma unroll
    for (int r = 0; r < 4; r++) {
        float inv = 1.f / accL[r];
        int n = qt*64 + w*16 + quad*4 + r;
        #pragma unroll
        for (int di = 0; di < 4; di++) {
            int c = h*64 + di*16 + ln;
            size_t gi = ((size_t)b*NN + n)*DIM + c;
            float o = accO[di][r]*inv + bf2f(As[gi]);
            attp[gi] = f2bf(o);
        }
    }
}

// ---------------------------------------------------------------------------
extern "C" void kernel_launch(void* const* d_in, const int* in_sizes, int n_in,
                              void* d_out, int out_size, void* d_ws, size_t ws_size,
                              hipStream_t stream) {
    const float* y2f = (const float*)d_in[0];
    const float* y2b = (const float*)d_in[1];
    const float* Wq  = (const float*)d_in[2];
    const float* bq  = (const float*)d_in[3];
    const float* Wk  = (const float*)d_in[4];
    const float* bk  = (const float*)d_in[5];
    const float* Wv  = (const float*)d_in[6];
    const float* bv  = (const float*)d_in[7];
    const float* Wo  = (const float*)d_in[8];
    const float* bo  = (const float*)d_in[9];
    float* out = (float*)d_out;

    const size_t NACT = (size_t)M_ROWS * DIM;  // 4,194,304 (8 MB as ushort)
    unsigned short* ws   = (unsigned short*)d_ws;
    unsigned short* Af   = ws;
    unsigned short* Ab   = ws + NACT;
    unsigned short* As   = ws + 2*NACT;
    unsigned short* Qh   = ws + 3*NACT;
    unsigned short* Kh   = ws + 4*NACT;
    unsigned short* Vt   = ws + 5*NACT;   // V written pre-transposed [b,h,d,n]
    unsigned short* Wt   = ws + 6*NACT;   // 4 x 1024 x 1024 bf16
    unsigned short* attp = Ab;            // overlay (Ab dead after QKV gemm)

    prep_w<<<dim3(32, 32, 4), 256, 0, stream>>>(Wq, Wk, Wv, Wo, Wt);
    prep_act<<<dim3(2048), 256, 0, stream>>>(y2f, y2b, Af, Ab, As);
    gemm_qkv<<<dim3(32, 24), 256, 0, stream>>>(
        Af, Ab, As, Wt, bq, bk, bv, Qh, Kh, Vt);
    attn_kernel<<<dim3(32, 32), 256, 0, stream>>>(Qh, Kh, Vt, As, attp);
    gemm_out<<<dim3(64, 8), 256, 0, stream>>>(attp, Wt, bo, out);
}